// Round 1
// baseline (1319.028 us; speedup 1.0000x reference)
//
#include <hip/hip_runtime.h>

typedef unsigned short u16;
typedef short v8s __attribute__((ext_vector_type(8)));
typedef float v4f __attribute__((ext_vector_type(4)));

union U16x8 { uint4 u4; v8s s8; u16 us[8]; };

__device__ __forceinline__ u16 f2bf(float x) {
  unsigned int u = __float_as_uint(x);
  u += 0x7fffu + ((u >> 16) & 1u);
  return (u16)(u >> 16);
}
__device__ __forceinline__ float bf2f(u16 h) {
  return __uint_as_float(((unsigned int)h) << 16);
}

// ---------------- constants ----------------
#define BB 32
#define NN 4096
#define DD 256
#define M_TOT 672
#define M_PAD 704
// flash tiling
#define MT 64      // m per workgroup
#define TN 64      // n per tile
#define XROW_S 264 // lds stride (bf16) for X row-major tile
#define XT_S 72    // lds stride for transposed tile & P

// ---------------- K0: Q_all[m] = codes @ Wq^T + bq ----------------
__global__ void k0_q(const float* __restrict__ cat, const float* __restrict__ typ,
                     const float* __restrict__ var, const float* __restrict__ spc,
                     const float* __restrict__ Wcat, const float* __restrict__ bcat,
                     const float* __restrict__ Wtype, const float* __restrict__ btype,
                     const float* __restrict__ Wvar, const float* __restrict__ bvar,
                     const float* __restrict__ Wsp, const float* __restrict__ bsp,
                     float* __restrict__ Qall) {
  __shared__ float cl[DD];
  const int m = blockIdx.x, tid = threadIdx.x;
  const float* codes = nullptr; const float* W = nullptr; const float* bia = nullptr; int r = 0;
  if (m < 16)       { codes = cat; r = m;       W = Wcat;  bia = bcat; }
  else if (m < 144) { codes = typ; r = m - 16;  W = Wtype; bia = btype; }
  else if (m < 656) { codes = var; r = m - 144; W = Wvar;  bia = bvar; }
  else if (m < 672) { codes = spc; r = m - 656; W = Wsp;   bia = bsp; }
  cl[tid] = (m < M_TOT) ? codes[r * DD + tid] : 0.f;
  __syncthreads();
  if (m < M_TOT) {
    float acc = bia[tid];
    for (int k = 0; k < DD; ++k) acc += cl[k] * W[tid * DD + k];
    Qall[m * DD + tid] = acc;
  } else {
    Qall[m * DD + tid] = 0.f;
  }
}

// ---------------- K1: Qp = Qall @ Wk (bf16), qb = Qall . bk ----------------
__global__ void k1_qp(const float* __restrict__ Qall, const float* __restrict__ Wk,
                      const float* __restrict__ bk, u16* __restrict__ Qp,
                      float* __restrict__ qbw) {
  __shared__ float ql[DD];
  __shared__ float red[4];
  const int m = blockIdx.x, tid = threadIdx.x;
  ql[tid] = Qall[m * DD + tid];
  __syncthreads();
  float acc = 0.f;
  for (int j = 0; j < DD; ++j) acc += ql[j] * Wk[j * DD + tid];
  Qp[m * DD + tid] = f2bf(acc);
  float p = ql[tid] * bk[tid];
  #pragma unroll
  for (int off = 32; off > 0; off >>= 1) p += __shfl_down(p, off, 64);
  if ((tid & 63) == 0) red[tid >> 6] = p;
  __syncthreads();
  if (tid == 0) qbw[m] = red[0] + red[1] + red[2] + red[3];
}

// ---------------- K2: X fp32 -> bf16 in two layouts ----------------
__global__ void k2_cast(const float* __restrict__ X, u16* __restrict__ Xb,
                        u16* __restrict__ XbT) {
  __shared__ u16 tl[64][72];
  const int n0 = blockIdx.x * 64, d0 = blockIdx.y * 64, b = blockIdx.z;
  const int tid = threadIdx.x;
  const int nl = tid >> 4, d4 = tid & 15;
  #pragma unroll
  for (int rr = 0; rr < 4; ++rr) {
    const int n = n0 + nl + rr * 16;
    float4 v = *(const float4*)(X + ((size_t)b * NN + n) * DD + d0 + d4 * 4);
    ushort4 h;
    h.x = f2bf(v.x); h.y = f2bf(v.y); h.z = f2bf(v.z); h.w = f2bf(v.w);
    *(ushort4*)(Xb + ((size_t)b * NN + n) * DD + d0 + d4 * 4) = h;
    *(ushort4*)(&tl[nl + rr * 16][d4 * 4]) = h;
  }
  __syncthreads();
  const int dl = tid >> 4, n4 = tid & 15;
  #pragma unroll
  for (int rr = 0; rr < 4; ++rr) {
    const int d = dl + rr * 16;
    ushort4 h;
    h.x = tl[n4 * 4 + 0][d]; h.y = tl[n4 * 4 + 1][d];
    h.z = tl[n4 * 4 + 2][d]; h.w = tl[n4 * 4 + 3][d];
    *(ushort4*)(XbT + ((size_t)b * DD + d0 + d) * NN + n0 + n4 * 4) = h;
  }
}

// ---------------- K3: flash attention levels (bf16 MFMA) ----------------
__global__ __launch_bounds__(256, 2) void k3_flash(
    const u16* __restrict__ Xb, const u16* __restrict__ XbT,
    const u16* __restrict__ Qp, const float* __restrict__ qbw,
    const unsigned char* __restrict__ mask, float* __restrict__ Hws) {
  __shared__ u16 sXrow[64 * XROW_S];  // 33792 B
  __shared__ u16 sXT[256 * XT_S];     // 36864 B
  __shared__ u16 sP[64 * XT_S];       // 9216 B
  __shared__ float sQb[64];
  __shared__ float sMask[64];

  const int tid = threadIdx.x;
  const int lane = tid & 63, w = tid >> 6;
  const int q = lane >> 4, c16 = lane & 15;
  const int b = blockIdx.x & 31, mt = blockIdx.x >> 5;
  const int m0 = mt * MT;

  // A fragments (Qp rows for this wave) stay in registers for the whole kernel
  v8s aQ[8];
  {
    const u16* qrow = Qp + (size_t)(m0 + w * 16 + c16) * DD + q * 8;
    #pragma unroll
    for (int ks = 0; ks < 8; ++ks) {
      U16x8 u; u.u4 = *(const uint4*)(qrow + ks * 32);
      aQ[ks] = u.s8;
    }
  }
  if (tid < 64) sQb[tid] = qbw[m0 + tid];

  v4f hacc[16];
  #pragma unroll
  for (int i = 0; i < 16; ++i) hacc[i] = (v4f){0.f, 0.f, 0.f, 0.f};
  float psum = 0.f;
  const int srow = tid >> 2, spart = tid & 3;

  const size_t xbase = (size_t)b * NN * DD;
  const size_t tbase = (size_t)b * DD * NN;
  uint4 rx[8], rt[8];
  unsigned char mreg = 0;

  auto prefetch = [&](int t) {
    const int n0 = t * TN;
    #pragma unroll
    for (int i = 0; i < 8; ++i) {
      const int c = tid + i * 256;           // 0..2047
      const int nl = c >> 5, k8 = c & 31;
      rx[i] = *(const uint4*)(Xb + xbase + (size_t)(n0 + nl) * DD + k8 * 8);
    }
    #pragma unroll
    for (int i = 0; i < 8; ++i) {
      const int c = tid + i * 256;
      const int dd = c >> 3, n8 = c & 7;
      rt[i] = *(const uint4*)(XbT + tbase + (size_t)dd * NN + n0 + n8 * 8);
    }
    if (tid < 64) mreg = mask[(size_t)b * NN + n0 + tid];
  };

  prefetch(0);
  __syncthreads();
  float qbr[4];
  #pragma unroll
  for (int r = 0; r < 4; ++r) qbr[r] = sQb[w * 16 + q * 4 + r];

  for (int t = 0; t < NN / TN; ++t) {
    __syncthreads();  // previous tile's LDS consumers done
    #pragma unroll
    for (int i = 0; i < 8; ++i) {
      const int c = tid + i * 256;
      const int nl = c >> 5, k8 = c & 31;
      *(uint4*)(sXrow + nl * XROW_S + k8 * 8) = rx[i];
    }
    #pragma unroll
    for (int i = 0; i < 8; ++i) {
      const int c = tid + i * 256;
      const int dd = c >> 3, n8 = c & 7;
      *(uint4*)(sXT + dd * XT_S + n8 * 8) = rt[i];
    }
    if (tid < 64) sMask[tid] = mreg ? 1.f : 0.f;
    __syncthreads();
    if (t < NN / TN - 1) prefetch(t + 1);

    // ---- S = Qp . X^T ----
    v4f sacc[4];
    #pragma unroll
    for (int s = 0; s < 4; ++s) sacc[s] = (v4f){0.f, 0.f, 0.f, 0.f};
    #pragma unroll
    for (int ks = 0; ks < 8; ++ks) {
      #pragma unroll
      for (int sub = 0; sub < 4; ++sub) {
        U16x8 u;
        u.u4 = *(const uint4*)(sXrow + (sub * 16 + c16) * XROW_S + ks * 32 + q * 8);
        sacc[sub] = __builtin_amdgcn_mfma_f32_16x16x32_bf16(aQ[ks], u.s8, sacc[sub], 0, 0, 0);
      }
    }
    // ---- P = exp(clip(mask(S/16)))  -> LDS (bf16) ----
    #pragma unroll
    for (int sub = 0; sub < 4; ++sub) {
      const int ncol = sub * 16 + c16;
      const float mk = sMask[ncol];
      #pragma unroll
      for (int r = 0; r < 4; ++r) {
        float s = (sacc[sub][r] + qbr[r]) * 0.0625f;
        s = fminf(fmaxf(s, -50.f), 50.f);
        s = (mk != 0.f) ? s : -50.f;
        sP[(w * 16 + q * 4 + r) * XT_S + ncol] = f2bf(__expf(s));
      }
    }
    __syncthreads();
    // ---- H += P . X ---- (plus running row-sums of P)
    v8s pf[2];
    #pragma unroll
    for (int kk = 0; kk < 2; ++kk) {
      U16x8 u;
      u.u4 = *(const uint4*)(sP + (w * 16 + c16) * XT_S + kk * 32 + q * 8);
      pf[kk] = u.s8;
    }
    #pragma unroll
    for (int i = 0; i < 16; ++i) psum += bf2f(sP[srow * XT_S + spart * 16 + i]);
    #pragma unroll
    for (int dt = 0; dt < 16; ++dt) {
      #pragma unroll
      for (int kk = 0; kk < 2; ++kk) {
        U16x8 u;
        u.u4 = *(const uint4*)(sXT + (dt * 16 + c16) * XT_S + kk * 32 + q * 8);
        hacc[dt] = __builtin_amdgcn_mfma_f32_16x16x32_bf16(pf[kk], u.s8, hacc[dt], 0, 0, 0);
      }
    }
  }

  // ---- epilogue: H / sumexp ----
  __syncthreads();
  float* sump = (float*)sXrow;        // alias (staging done)
  sump[tid] = psum;
  __syncthreads();
  float* sumv = ((float*)sXrow) + 256;
  if (tid < 64)
    sumv[tid] = sump[tid * 4] + sump[tid * 4 + 1] + sump[tid * 4 + 2] + sump[tid * 4 + 3];
  __syncthreads();
  float sv[4];
  #pragma unroll
  for (int r = 0; r < 4; ++r) sv[r] = sumv[w * 16 + q * 4 + r];
  #pragma unroll
  for (int dt = 0; dt < 16; ++dt) {
    #pragma unroll
    for (int r = 0; r < 4; ++r) {
      Hws[((size_t)b * M_PAD + m0 + w * 16 + q * 4 + r) * DD + dt * 16 + c16] =
          hacc[dt][r] / sv[r];
    }
  }
}

// ---------------- K4: masked position pooling partials ----------------
__global__ void k4_pool(const float* __restrict__ pos, const unsigned char* __restrict__ mask,
                        float* __restrict__ pp, float* __restrict__ cnt) {
  __shared__ float mf[256];
  const int cx = blockIdx.x, b = blockIdx.y, tid = threadIdx.x;
  const int n0 = cx * 256;
  mf[tid] = mask[(size_t)b * NN + n0 + tid] ? 1.f : 0.f;
  __syncthreads();
  float acc = 0.f;
  for (int n = 0; n < 256; ++n)
    acc += mf[n] * pos[((size_t)b * NN + n0 + n) * DD + tid];
  pp[((size_t)b * 16 + cx) * DD + tid] = acc;
  if (tid == 0) {
    float c = 0.f;
    for (int n = 0; n < 256; ++n) c += mf[n];
    cnt[b * 16 + cx] = c;
  }
}

// ---------------- K5: gating chain + MLP + LayerNorm ----------------
__device__ void softmax_sparsify(const float* in, int nn, float* outp, float thr) {
  float mx = -3.4e38f;
  for (int i = 0; i < nn; ++i) mx = fmaxf(mx, in[i]);
  float s = 0.f;
  for (int i = 0; i < nn; ++i) { float e = __expf(in[i] - mx); outp[i] = e; s += e; }
  float s2 = 0.f;
  for (int i = 0; i < nn; ++i) {
    float v = outp[i] / s;
    v = (v > thr) ? v : 0.f;
    outp[i] = v; s2 += v;
  }
  const float inv = 1.f / (s2 + 1e-8f);
  for (int i = 0; i < nn; ++i) outp[i] *= inv;
}

__global__ void k5_final(const float* __restrict__ Hws, const float* __restrict__ pp,
                         const float* __restrict__ cnt, const float* __restrict__ log_tau,
                         const float* __restrict__ Wg1, const float* __restrict__ bg1,
                         const float* __restrict__ Wg2, const float* __restrict__ bg2,
                         const float* __restrict__ Wo, const float* __restrict__ bo,
                         const float* __restrict__ lng, const float* __restrict__ lnb,
                         const float* __restrict__ lvlw, float* __restrict__ out) {
  __shared__ float wr[M_TOT];
  __shared__ float wcat[16], wtyp[128], wvar[512], wsp[16], lw[4];
  __shared__ float wbuf[M_TOT];
  __shared__ float zb[DD], pb[DD], hb[DD], zg[DD];
  __shared__ float red[8];
  const int b = blockIdx.x, tid = threadIdx.x;
  const int lane = tid & 63, w = tid >> 6;
  const float tau = fminf(fmaxf(__expf(log_tau[0]) + 0.1f, 0.1f), 2.0f);
  const float* Hb = Hws + (size_t)b * M_PAD * DD;

  for (int m = w; m < M_TOT; m += 4) {
    float4 v = *(const float4*)(Hb + (size_t)m * DD + lane * 4);
    float s = v.x * v.x + v.y * v.y + v.z * v.z + v.w * v.w;
    #pragma unroll
    for (int off = 32; off > 0; off >>= 1) s += __shfl_xor(s, off, 64);
    if (lane == 0) wr[m] = sqrtf(s) / tau;
  }
  __syncthreads();

  if (tid == 0) {
    // level 0: category
    softmax_sparsify(wr, 16, wcat, 0.1f);
    // level 1: type, gated by category (raw * gate, then softmax)
    for (int i = 0; i < 128; ++i) wbuf[i] = wr[16 + i] * wcat[i >> 3];
    softmax_sparsify(wbuf, 128, wtyp, 0.05f);
    // level 2: variant, gated by type
    for (int i = 0; i < 512; ++i) wvar[i] = wr[144 + i] * wtyp[i >> 2];
    softmax_sparsify(wvar, 512, wvar, 0.025f);
    // spatial
    softmax_sparsify(wr + 656, 16, wsp, 0.1f);
    // level weights
    float mx = fmaxf(fmaxf(lvlw[0], lvlw[1]), fmaxf(lvlw[2], lvlw[3]));
    float s = 0.f;
    for (int i = 0; i < 4; ++i) { lw[i] = __expf(lvlw[i] - mx); s += lw[i]; }
    for (int i = 0; i < 4; ++i) lw[i] /= s;
  }
  __syncthreads();

  for (int m = tid; m < M_TOT; m += 256) {
    float v;
    if (m < 16)       v = lw[0] * wcat[m];
    else if (m < 144) v = lw[1] * wtyp[m - 16];
    else if (m < 656) v = lw[2] * wvar[m - 144];
    else              v = lw[3] * wsp[m - 656];
    wbuf[m] = v;
  }
  __syncthreads();

  float z = 0.f;
  for (int m = 0; m < M_TOT; ++m) z += wbuf[m] * Hb[(size_t)m * DD + tid];
  float p = 0.f, c = 0.f;
  for (int ch = 0; ch < 16; ++ch) {
    p += pp[((size_t)b * 16 + ch) * DD + tid];
    c += cnt[b * 16 + ch];
  }
  p /= (c + 1e-8f);
  zb[tid] = z; pb[tid] = p;
  __syncthreads();

  float h = bg1[tid];
  for (int k = 0; k < DD; ++k) h += zb[k] * Wg1[(size_t)tid * 512 + k];
  for (int k = 0; k < DD; ++k) h += pb[k] * Wg1[(size_t)tid * 512 + 256 + k];
  h = 0.5f * h * (1.f + erff(h * 0.70710678118654752f));
  hb[tid] = h;
  __syncthreads();

  float g = bg2[tid];
  for (int k = 0; k < DD; ++k) g += hb[k] * Wg2[(size_t)tid * DD + k];
  g = 1.f / (1.f + __expf(-g));
  zg[tid] = zb[tid] * g;
  __syncthreads();

  float y = bo[tid];
  for (int k = 0; k < DD; ++k) y += zg[k] * Wo[(size_t)tid * DD + k];

  float s = y;
  #pragma unroll
  for (int off = 32; off > 0; off >>= 1) s += __shfl_xor(s, off, 64);
  if (lane == 0) red[w] = s;
  __syncthreads();
  const float mu = (red[0] + red[1] + red[2] + red[3]) * (1.f / 256.f);
  float dv = (y - mu) * (y - mu);
  #pragma unroll
  for (int off = 32; off > 0; off >>= 1) dv += __shfl_xor(dv, off, 64);
  if (lane == 0) red[4 + w] = dv;
  __syncthreads();
  const float var = (red[4] + red[5] + red[6] + red[7]) * (1.f / 256.f);
  out[(size_t)b * DD + tid] = (y - mu) / sqrtf(var + 1e-5f) * lng[tid] + lnb[tid];
}

// ---------------- launch ----------------
extern "C" void kernel_launch(void* const* d_in, const int* in_sizes, int n_in,
                              void* d_out, int out_size, void* d_ws, size_t ws_size,
                              hipStream_t stream) {
  const float* X          = (const float*)d_in[0];
  const float* positions  = (const float*)d_in[1];
  const unsigned char* mask = (const unsigned char*)d_in[2];
  const float* cat  = (const float*)d_in[3];
  const float* typ  = (const float*)d_in[4];
  const float* var  = (const float*)d_in[5];
  const float* spc  = (const float*)d_in[6];
  const float* log_tau = (const float*)d_in[7];
  const float* Wk   = (const float*)d_in[8];   const float* bk    = (const float*)d_in[9];
  const float* Wcat = (const float*)d_in[10];  const float* bcat  = (const float*)d_in[11];
  const float* Wtype= (const float*)d_in[12];  const float* btype = (const float*)d_in[13];
  const float* Wvar = (const float*)d_in[14];  const float* bvar  = (const float*)d_in[15];
  const float* Wsp  = (const float*)d_in[16];  const float* bsp   = (const float*)d_in[17];
  const float* Wg1  = (const float*)d_in[18];  const float* bg1   = (const float*)d_in[19];
  const float* Wg2  = (const float*)d_in[20];  const float* bg2   = (const float*)d_in[21];
  const float* Wo   = (const float*)d_in[22];  const float* bo    = (const float*)d_in[23];
  const float* lng  = (const float*)d_in[24];  const float* lnb   = (const float*)d_in[25];
  const float* lvlw = (const float*)d_in[26];

  char* ws = (char*)d_ws;
  const size_t oXb   = 0;                       // 32*4096*256*2 = 64 MiB
  const size_t oXT   = oXb + 67108864;          // 64 MiB
  const size_t oQall = oXT + 67108864;          // 704*256*4
  const size_t oQp   = oQall + 720896;          // 704*256*2
  const size_t oQb   = oQp + 360448;            // 704*4
  const size_t oH    = oQb + 2816;              // 32*704*256*4
  const size_t oPP   = oH + 23068672;           // 32*16*256*4
  const size_t oCNT  = oPP + 524288;            // 32*16*4

  u16*   Xb   = (u16*)(ws + oXb);
  u16*   XbT  = (u16*)(ws + oXT);
  float* Qall = (float*)(ws + oQall);
  u16*   Qp   = (u16*)(ws + oQp);
  float* qbw  = (float*)(ws + oQb);
  float* Hws  = (float*)(ws + oH);
  float* ppw  = (float*)(ws + oPP);
  float* cntw = (float*)(ws + oCNT);

  k0_q<<<M_PAD, 256, 0, stream>>>(cat, typ, var, spc, Wcat, bcat, Wtype, btype,
                                  Wvar, bvar, Wsp, bsp, Qall);
  k1_qp<<<M_PAD, 256, 0, stream>>>(Qall, Wk, bk, Qp, qbw);
  k2_cast<<<dim3(64, 4, 32), 256, 0, stream>>>(X, Xb, XbT);
  k3_flash<<<(M_PAD / MT) * 32, 256, 0, stream>>>(Xb, XbT, Qp, qbw, mask, Hws);
  k4_pool<<<dim3(16, 32), 256, 0, stream>>>(positions, mask, ppw, cntw);
  k5_final<<<32, 256, 0, stream>>>(Hws, ppw, cntw, log_tau, Wg1, bg1, Wg2, bg2,
                                   Wo, bo, lng, lnb, lvlw, (float*)d_out);
}

// Round 2
// 850.075 us; speedup vs baseline: 1.5517x; 1.5517x over previous
//
#include <hip/hip_runtime.h>

typedef unsigned short u16;
typedef short v8s __attribute__((ext_vector_type(8)));
typedef float v4f __attribute__((ext_vector_type(4)));

union U16x8 { uint4 u4; v8s s8; u16 us[8]; };

__device__ __forceinline__ u16 f2bf(float x) {
  unsigned int u = __float_as_uint(x);
  u += 0x7fffu + ((u >> 16) & 1u);
  return (u16)(u >> 16);
}

#define GLOBAL_AS __attribute__((address_space(1)))
#define LDS_AS __attribute__((address_space(3)))
__device__ __forceinline__ void async16(const void* g, void* l) {
  __builtin_amdgcn_global_load_lds((const GLOBAL_AS unsigned int*)g,
                                   (LDS_AS unsigned int*)l, 16, 0, 0);
}

// ---------------- constants ----------------
#define BB 32
#define NN 4096
#define DD 256
#define M_TOT 672
#define M_PAD 704
#define CHUNK_B 16   // batches per P-chunk

// ---------------- KZ: zero sums+nrm ----------------
__global__ void kz_zero(float* __restrict__ p, int n) {
  int i = blockIdx.x * 256 + threadIdx.x;
  if (i < n) p[i] = 0.f;
}

// ---------------- K0: Q_all[m] = codes @ Wq^T + bq ----------------
__global__ void k0_q(const float* __restrict__ cat, const float* __restrict__ typ,
                     const float* __restrict__ var, const float* __restrict__ spc,
                     const float* __restrict__ Wcat, const float* __restrict__ bcat,
                     const float* __restrict__ Wtype, const float* __restrict__ btype,
                     const float* __restrict__ Wvar, const float* __restrict__ bvar,
                     const float* __restrict__ Wsp, const float* __restrict__ bsp,
                     float* __restrict__ Qall) {
  __shared__ float cl[DD];
  const int m = blockIdx.x, tid = threadIdx.x;
  const float* codes = nullptr; const float* W = nullptr; const float* bia = nullptr; int r = 0;
  if (m < 16)       { codes = cat; r = m;       W = Wcat;  bia = bcat; }
  else if (m < 144) { codes = typ; r = m - 16;  W = Wtype; bia = btype; }
  else if (m < 656) { codes = var; r = m - 144; W = Wvar;  bia = bvar; }
  else if (m < 672) { codes = spc; r = m - 656; W = Wsp;   bia = bsp; }
  cl[tid] = (m < M_TOT) ? codes[r * DD + tid] : 0.f;
  __syncthreads();
  if (m < M_TOT) {
    float acc = bia[tid];
    const float4* w4 = (const float4*)(W + (size_t)tid * DD);
    const float4* c4 = (const float4*)cl;
    #pragma unroll 8
    for (int k = 0; k < 64; ++k) {
      float4 a = c4[k], b = w4[k];
      acc += a.x * b.x + a.y * b.y + a.z * b.z + a.w * b.w;
    }
    Qall[m * DD + tid] = acc;
  } else {
    Qall[m * DD + tid] = 0.f;
  }
}

// ---------------- K1: Qp = Qall @ Wk (bf16), qbw = Qall . bk ----------------
__global__ void k1_qp(const float* __restrict__ Qall, const float* __restrict__ Wk,
                      const float* __restrict__ bk, u16* __restrict__ Qp,
                      float* __restrict__ qbw) {
  __shared__ float ql[DD];
  __shared__ float red[4];
  const int m = blockIdx.x, tid = threadIdx.x;
  ql[tid] = Qall[m * DD + tid];
  __syncthreads();
  float acc = 0.f;
  for (int j = 0; j < DD; ++j) acc += ql[j] * Wk[(size_t)j * DD + tid];
  Qp[m * DD + tid] = f2bf(acc);
  float p = ql[tid] * bk[tid];
  #pragma unroll
  for (int off = 32; off > 0; off >>= 1) p += __shfl_down(p, off, 64);
  if ((tid & 63) == 0) red[tid >> 6] = p;
  __syncthreads();
  if (tid == 0) qbw[m] = red[0] + red[1] + red[2] + red[3];
}

// ---------------- K2: X fp32 -> bf16 in two layouts ----------------
__global__ void k2_cast(const float* __restrict__ X, u16* __restrict__ Xb,
                        u16* __restrict__ XbT) {
  __shared__ u16 tl[64][72];
  const int n0 = blockIdx.x * 64, d0 = blockIdx.y * 64, b = blockIdx.z;
  const int tid = threadIdx.x;
  const int nl = tid >> 4, d4 = tid & 15;
  #pragma unroll
  for (int rr = 0; rr < 4; ++rr) {
    const int n = n0 + nl + rr * 16;
    float4 v = *(const float4*)(X + ((size_t)b * NN + n) * DD + d0 + d4 * 4);
    ushort4 h;
    h.x = f2bf(v.x); h.y = f2bf(v.y); h.z = f2bf(v.z); h.w = f2bf(v.w);
    *(ushort4*)(Xb + ((size_t)b * NN + n) * DD + d0 + d4 * 4) = h;
    *(ushort4*)(&tl[nl + rr * 16][d4 * 4]) = h;
  }
  __syncthreads();
  const int dl = tid >> 4, n4 = tid & 15;
  #pragma unroll
  for (int rr = 0; rr < 4; ++rr) {
    const int d = dl + rr * 16;
    ushort4 h;
    h.x = tl[n4 * 4 + 0][d]; h.y = tl[n4 * 4 + 1][d];
    h.z = tl[n4 * 4 + 2][d]; h.w = tl[n4 * 4 + 3][d];
    *(ushort4*)(XbT + ((size_t)b * DD + d0 + d) * NN + n0 + n4 * 4) = h;
  }
}

// ---------------- P1: P = exp(clip(Qp.Xb^T/16 + qb)), rowsums ----------------
// tile 128m x 128n, BK=64, 4 waves 2x2 (64x64 each), 16x16x32 MFMA
__global__ __launch_bounds__(256, 2) void p1_scores(
    const u16* __restrict__ Xb, const u16* __restrict__ Qp,
    const float* __restrict__ qbw, const unsigned char* __restrict__ mask,
    u16* __restrict__ P, float* __restrict__ sums, int b0) {
  __shared__ u16 sA[128 * 64];  // 16 KB
  __shared__ u16 sB[128 * 64];  // 16 KB
  const int tid = threadIdx.x;
  const int lane = tid & 63, w = tid >> 6;
  const int q = lane >> 4, c16 = lane & 15;
  const int n0 = blockIdx.x * 128, m0 = blockIdx.y * 128;
  const int b = b0 + blockIdx.z;
  const int wm = (w >> 1) * 64, wn = (w & 1) * 64;

  float qv[4][4];
  unsigned char mk[4];
  #pragma unroll
  for (int mi = 0; mi < 4; ++mi)
    #pragma unroll
    for (int r = 0; r < 4; ++r) {
      int row = m0 + wm + mi * 16 + q * 4 + r;
      qv[mi][r] = qbw[row < M_PAD ? row : M_PAD - 1];
    }
  #pragma unroll
  for (int ni = 0; ni < 4; ++ni)
    mk[ni] = mask[(size_t)b * NN + n0 + wn + ni * 16 + c16];

  v4f acc[4][4];
  #pragma unroll
  for (int mi = 0; mi < 4; ++mi)
    #pragma unroll
    for (int ni = 0; ni < 4; ++ni) acc[mi][ni] = (v4f){0.f, 0.f, 0.f, 0.f};

  const u16* Xbase = Xb + (size_t)b * NN * DD;
  for (int ks = 0; ks < 4; ++ks) {
    __syncthreads();
    #pragma unroll
    for (int i = 0; i < 4; ++i) {
      const int c = i * 256 + tid;
      const int row = c >> 3, kc = (c & 7) * 8;
      int gm = m0 + row; gm = gm < M_PAD ? gm : M_PAD - 1;
      async16(Qp + (size_t)gm * DD + ks * 64 + kc, sA + c * 8);
      async16(Xbase + (size_t)(n0 + row) * DD + ks * 64 + kc, sB + c * 8);
    }
    __syncthreads();
    #pragma unroll
    for (int kk = 0; kk < 2; ++kk) {
      v8s af[4], bf[4];
      #pragma unroll
      for (int mi = 0; mi < 4; ++mi) {
        U16x8 u; u.u4 = *(const uint4*)(sA + (wm + mi * 16 + c16) * 64 + kk * 32 + q * 8);
        af[mi] = u.s8;
      }
      #pragma unroll
      for (int ni = 0; ni < 4; ++ni) {
        U16x8 u; u.u4 = *(const uint4*)(sB + (wn + ni * 16 + c16) * 64 + kk * 32 + q * 8);
        bf[ni] = u.s8;
      }
      #pragma unroll
      for (int mi = 0; mi < 4; ++mi)
        #pragma unroll
        for (int ni = 0; ni < 4; ++ni)
          acc[mi][ni] = __builtin_amdgcn_mfma_f32_16x16x32_bf16(af[mi], bf[ni], acc[mi][ni], 0, 0, 0);
    }
  }

  // epilogue: exp + store P + rowsums
  float rs[4][4];
  #pragma unroll
  for (int mi = 0; mi < 4; ++mi)
    #pragma unroll
    for (int r = 0; r < 4; ++r) rs[mi][r] = 0.f;

  #pragma unroll
  for (int mi = 0; mi < 4; ++mi) {
    #pragma unroll
    for (int ni = 0; ni < 4; ++ni) {
      #pragma unroll
      for (int r = 0; r < 4; ++r) {
        float s = (acc[mi][ni][r] + qv[mi][r]) * 0.0625f;
        s = fminf(fmaxf(s, -50.f), 50.f);
        s = mk[ni] ? s : -50.f;
        float p = __expf(s);
        rs[mi][r] += p;
        const int row = m0 + wm + mi * 16 + q * 4 + r;
        if (row < M_TOT)
          P[((size_t)(b - b0) * M_TOT + row) * NN + n0 + wn + ni * 16 + c16] = f2bf(p);
      }
    }
  }
  #pragma unroll
  for (int mi = 0; mi < 4; ++mi) {
    #pragma unroll
    for (int r = 0; r < 4; ++r) {
      float v = rs[mi][r];
      v += __shfl_xor(v, 1, 64);
      v += __shfl_xor(v, 2, 64);
      v += __shfl_xor(v, 4, 64);
      v += __shfl_xor(v, 8, 64);
      const int row = m0 + wm + mi * 16 + q * 4 + r;
      if (c16 == 0 && row < M_TOT)
        atomicAdd(&sums[(size_t)b * M_PAD + row], v);
    }
  }
}

// ---------------- P2: H = (P . XbT^T)/sums, norm partials ----------------
// tile 64m x 128d, BK=64 (contraction over n), 4 waves 2x2 (32x64 each)
__global__ __launch_bounds__(256, 4) void p2_h(
    const u16* __restrict__ P, const u16* __restrict__ XbT,
    const float* __restrict__ sums, float* __restrict__ Hws,
    float* __restrict__ nrm, int b0) {
  __shared__ u16 sA[64 * 64];   // 8 KB
  __shared__ u16 sB[128 * 64];  // 16 KB
  const int tid = threadIdx.x;
  const int lane = tid & 63, w = tid >> 6;
  const int q = lane >> 4, c16 = lane & 15;
  const int d0 = blockIdx.x * 128, m0 = blockIdx.y * 64;
  const int b = b0 + blockIdx.z;
  const int wm = (w >> 1) * 32, wd = (w & 1) * 64;

  v4f acc[2][4];
  #pragma unroll
  for (int mi = 0; mi < 2; ++mi)
    #pragma unroll
    for (int ni = 0; ni < 4; ++ni) acc[mi][ni] = (v4f){0.f, 0.f, 0.f, 0.f};

  const u16* Pb = P + (size_t)(b - b0) * M_TOT * NN;
  const u16* Tb = XbT + ((size_t)b * DD + d0) * NN;

  for (int ks = 0; ks < NN / 64; ++ks) {
    __syncthreads();
    #pragma unroll
    for (int i = 0; i < 2; ++i) {
      const int c = i * 256 + tid;
      const int row = c >> 3, kc = (c & 7) * 8;
      int gm = m0 + row; gm = gm < M_TOT ? gm : M_TOT - 1;
      async16(Pb + (size_t)gm * NN + ks * 64 + kc, sA + c * 8);
    }
    #pragma unroll
    for (int i = 0; i < 4; ++i) {
      const int c = i * 256 + tid;
      const int row = c >> 3, kc = (c & 7) * 8;
      async16(Tb + (size_t)row * NN + ks * 64 + kc, sB + c * 8);
    }
    __syncthreads();
    #pragma unroll
    for (int kk = 0; kk < 2; ++kk) {
      v8s af[2], bf[4];
      #pragma unroll
      for (int mi = 0; mi < 2; ++mi) {
        U16x8 u; u.u4 = *(const uint4*)(sA + (wm + mi * 16 + c16) * 64 + kk * 32 + q * 8);
        af[mi] = u.s8;
      }
      #pragma unroll
      for (int ni = 0; ni < 4; ++ni) {
        U16x8 u; u.u4 = *(const uint4*)(sB + (wd + ni * 16 + c16) * 64 + kk * 32 + q * 8);
        bf[ni] = u.s8;
      }
      #pragma unroll
      for (int mi = 0; mi < 2; ++mi)
        #pragma unroll
        for (int ni = 0; ni < 4; ++ni)
          acc[mi][ni] = __builtin_amdgcn_mfma_f32_16x16x32_bf16(af[mi], bf[ni], acc[mi][ni], 0, 0, 0);
    }
  }

  // epilogue: divide by sums, store H, accumulate norm^2
  float sv[2][4], ns[2][4];
  #pragma unroll
  for (int mi = 0; mi < 2; ++mi)
    #pragma unroll
    for (int r = 0; r < 4; ++r) {
      const int row = m0 + wm + mi * 16 + q * 4 + r;
      sv[mi][r] = sums[(size_t)b * M_PAD + row];
      ns[mi][r] = 0.f;
    }
  #pragma unroll
  for (int mi = 0; mi < 2; ++mi) {
    #pragma unroll
    for (int ni = 0; ni < 4; ++ni) {
      #pragma unroll
      for (int r = 0; r < 4; ++r) {
        const int row = m0 + wm + mi * 16 + q * 4 + r;
        float h = acc[mi][ni][r] / sv[mi][r];
        ns[mi][r] += h * h;
        Hws[((size_t)b * M_PAD + row) * DD + d0 + wd + ni * 16 + c16] = h;
      }
    }
  }
  #pragma unroll
  for (int mi = 0; mi < 2; ++mi) {
    #pragma unroll
    for (int r = 0; r < 4; ++r) {
      float v = ns[mi][r];
      v += __shfl_xor(v, 1, 64);
      v += __shfl_xor(v, 2, 64);
      v += __shfl_xor(v, 4, 64);
      v += __shfl_xor(v, 8, 64);
      const int row = m0 + wm + mi * 16 + q * 4 + r;
      if (c16 == 0 && row < M_TOT)
        atomicAdd(&nrm[(size_t)b * M_PAD + row], v);
    }
  }
}

// ---------------- K4: masked position pooling partials ----------------
__global__ void k4_pool(const float* __restrict__ pos, const unsigned char* __restrict__ mask,
                        float* __restrict__ pp, float* __restrict__ cnt) {
  __shared__ float sp[4][256];
  __shared__ float sc[4];
  const int cx = blockIdx.x, b = blockIdx.y, tid = threadIdx.x;
  const int nl = tid >> 6, d4 = tid & 63;
  const int n0 = cx * 256;
  float4 acc = {0.f, 0.f, 0.f, 0.f};
  float c = 0.f;
  for (int i = 0; i < 64; ++i) {
    const int n = n0 + i * 4 + nl;
    const float m = mask[(size_t)b * NN + n] ? 1.f : 0.f;
    c += m;
    float4 v = *(const float4*)(pos + ((size_t)b * NN + n) * DD + d4 * 4);
    acc.x += m * v.x; acc.y += m * v.y; acc.z += m * v.z; acc.w += m * v.w;
  }
  *(float4*)(&sp[nl][d4 * 4]) = acc;
  if (d4 == 0) sc[nl] = c;
  __syncthreads();
  pp[((size_t)b * 16 + cx) * DD + tid] = sp[0][tid] + sp[1][tid] + sp[2][tid] + sp[3][tid];
  if (tid == 0) cnt[b * 16 + cx] = sc[0] + sc[1] + sc[2] + sc[3];
}

// ---------------- K5: gating chain + MLP + LayerNorm ----------------
__device__ void softmax_sparsify(const float* in, int nn, float* outp, float thr) {
  float mx = -3.4e38f;
  for (int i = 0; i < nn; ++i) mx = fmaxf(mx, in[i]);
  float s = 0.f;
  for (int i = 0; i < nn; ++i) { float e = __expf(in[i] - mx); outp[i] = e; s += e; }
  float s2 = 0.f;
  for (int i = 0; i < nn; ++i) {
    float v = outp[i] / s;
    v = (v > thr) ? v : 0.f;
    outp[i] = v; s2 += v;
  }
  const float inv = 1.f / (s2 + 1e-8f);
  for (int i = 0; i < nn; ++i) outp[i] *= inv;
}

__global__ void k5_final(const float* __restrict__ Hws, const float* __restrict__ nrm,
                         const float* __restrict__ pp, const float* __restrict__ cnt,
                         const float* __restrict__ log_tau,
                         const float* __restrict__ Wg1, const float* __restrict__ bg1,
                         const float* __restrict__ Wg2, const float* __restrict__ bg2,
                         const float* __restrict__ Wo, const float* __restrict__ bo,
                         const float* __restrict__ lng, const float* __restrict__ lnb,
                         const float* __restrict__ lvlw, float* __restrict__ out) {
  __shared__ float wr[M_TOT];
  __shared__ float wcat[16], wtyp[128], wvar[512], wsp[16], lw[4];
  __shared__ float wbuf[M_TOT];
  __shared__ float zpart[4][DD];
  __shared__ float zb[DD], pb[DD], hb[DD], zg[DD];
  __shared__ float red[8];
  const int b = blockIdx.x, tid = threadIdx.x;
  const int lane = tid & 63, w = tid >> 6;
  const float tau = fminf(fmaxf(__expf(log_tau[0]) + 0.1f, 0.1f), 2.0f);
  const float* Hb = Hws + (size_t)b * M_PAD * DD;

  for (int m = tid; m < M_TOT; m += 256)
    wr[m] = sqrtf(nrm[(size_t)b * M_PAD + m]) / tau;
  __syncthreads();

  if (tid == 0) {
    softmax_sparsify(wr, 16, wcat, 0.1f);
    for (int i = 0; i < 128; ++i) wbuf[i] = wr[16 + i] * wcat[i >> 3];
    softmax_sparsify(wbuf, 128, wtyp, 0.05f);
    for (int i = 0; i < 512; ++i) wvar[i] = wr[144 + i] * wtyp[i >> 2];
    softmax_sparsify(wvar, 512, wvar, 0.025f);
    softmax_sparsify(wr + 656, 16, wsp, 0.1f);
    float mx = fmaxf(fmaxf(lvlw[0], lvlw[1]), fmaxf(lvlw[2], lvlw[3]));
    float s = 0.f;
    for (int i = 0; i < 4; ++i) { lw[i] = __expf(lvlw[i] - mx); s += lw[i]; }
    for (int i = 0; i < 4; ++i) lw[i] /= s;
  }
  __syncthreads();

  for (int m = tid; m < M_TOT; m += 256) {
    float v;
    if (m < 16)       v = lw[0] * wcat[m];
    else if (m < 144) v = lw[1] * wtyp[m - 16];
    else if (m < 656) v = lw[2] * wvar[m - 144];
    else              v = lw[3] * wsp[m - 656];
    wbuf[m] = v;
  }
  __syncthreads();

  // z = sum_m w[m] * H[m][:], wave-split over m
  {
    float4 zp = {0.f, 0.f, 0.f, 0.f};
    for (int m = w; m < M_TOT; m += 4) {
      const float wv = wbuf[m];
      float4 hv = *(const float4*)(Hb + (size_t)m * DD + lane * 4);
      zp.x += wv * hv.x; zp.y += wv * hv.y; zp.z += wv * hv.z; zp.w += wv * hv.w;
    }
    *(float4*)(&zpart[w][lane * 4]) = zp;
  }
  __syncthreads();
  float z = zpart[0][tid] + zpart[1][tid] + zpart[2][tid] + zpart[3][tid];
  float p = 0.f, c = 0.f;
  for (int ch = 0; ch < 16; ++ch) {
    p += pp[((size_t)b * 16 + ch) * DD + tid];
    c += cnt[b * 16 + ch];
  }
  p /= (c + 1e-8f);
  zb[tid] = z; pb[tid] = p;
  __syncthreads();

  float h = bg1[tid];
  {
    const float4* w4 = (const float4*)(Wg1 + (size_t)tid * 512);
    const float4* z4 = (const float4*)zb;
    const float4* p4 = (const float4*)pb;
    for (int k = 0; k < 64; ++k) {
      float4 a = z4[k], bb = w4[k];
      h += a.x * bb.x + a.y * bb.y + a.z * bb.z + a.w * bb.w;
    }
    for (int k = 0; k < 64; ++k) {
      float4 a = p4[k], bb = w4[64 + k];
      h += a.x * bb.x + a.y * bb.y + a.z * bb.z + a.w * bb.w;
    }
  }
  h = 0.5f * h * (1.f + erff(h * 0.70710678118654752f));
  hb[tid] = h;
  __syncthreads();

  float g = bg2[tid];
  {
    const float4* w4 = (const float4*)(Wg2 + (size_t)tid * DD);
    const float4* h4 = (const float4*)hb;
    for (int k = 0; k < 64; ++k) {
      float4 a = h4[k], bb = w4[k];
      g += a.x * bb.x + a.y * bb.y + a.z * bb.z + a.w * bb.w;
    }
  }
  g = 1.f / (1.f + __expf(-g));
  zg[tid] = zb[tid] * g;
  __syncthreads();

  float y = bo[tid];
  {
    const float4* w4 = (const float4*)(Wo + (size_t)tid * DD);
    const float4* z4 = (const float4*)zg;
    for (int k = 0; k < 64; ++k) {
      float4 a = z4[k], bb = w4[k];
      y += a.x * bb.x + a.y * bb.y + a.z * bb.z + a.w * bb.w;
    }
  }

  float s = y;
  #pragma unroll
  for (int off = 32; off > 0; off >>= 1) s += __shfl_xor(s, off, 64);
  if (lane == 0) red[w] = s;
  __syncthreads();
  const float mu = (red[0] + red[1] + red[2] + red[3]) * (1.f / 256.f);
  float dv = (y - mu) * (y - mu);
  #pragma unroll
  for (int off = 32; off > 0; off >>= 1) dv += __shfl_xor(dv, off, 64);
  if (lane == 0) red[4 + w] = dv;
  __syncthreads();
  const float var = (red[4] + red[5] + red[6] + red[7]) * (1.f / 256.f);
  out[(size_t)b * DD + tid] = (y - mu) / sqrtf(var + 1e-5f) * lng[tid] + lnb[tid];
}

// ---------------- launch ----------------
extern "C" void kernel_launch(void* const* d_in, const int* in_sizes, int n_in,
                              void* d_out, int out_size, void* d_ws, size_t ws_size,
                              hipStream_t stream) {
  const float* X          = (const float*)d_in[0];
  const float* positions  = (const float*)d_in[1];
  const unsigned char* mask = (const unsigned char*)d_in[2];
  const float* cat  = (const float*)d_in[3];
  const float* typ  = (const float*)d_in[4];
  const float* var  = (const float*)d_in[5];
  const float* spc  = (const float*)d_in[6];
  const float* log_tau = (const float*)d_in[7];
  const float* Wk   = (const float*)d_in[8];   const float* bk    = (const float*)d_in[9];
  const float* Wcat = (const float*)d_in[10];  const float* bcat  = (const float*)d_in[11];
  const float* Wtype= (const float*)d_in[12];  const float* btype = (const float*)d_in[13];
  const float* Wvar = (const float*)d_in[14];  const float* bvar  = (const float*)d_in[15];
  const float* Wsp  = (const float*)d_in[16];  const float* bsp   = (const float*)d_in[17];
  const float* Wg1  = (const float*)d_in[18];  const float* bg1   = (const float*)d_in[19];
  const float* Wg2  = (const float*)d_in[20];  const float* bg2   = (const float*)d_in[21];
  const float* Wo   = (const float*)d_in[22];  const float* bo    = (const float*)d_in[23];
  const float* lng  = (const float*)d_in[24];  const float* lnb   = (const float*)d_in[25];
  const float* lvlw = (const float*)d_in[26];

  char* ws = (char*)d_ws;
  const size_t oXb   = 0;                        // 64 MiB
  const size_t oXT   = oXb + 67108864;           // 64 MiB
  const size_t oP    = oXT + 67108864;           // 16*672*4096*2 = 84 MiB
  const size_t oQall = oP + 88080384;
  const size_t oQp   = oQall + 720896;
  const size_t oQb   = oQp + 360448;
  const size_t oSums = oQb + 2816;               // 32*704*4
  const size_t oNrm  = oSums + 90112;            // 32*704*4
  const size_t oH    = oNrm + 90112;             // 32*704*256*4 = 22 MiB
  const size_t oPP   = oH + 23068672;
  const size_t oCNT  = oPP + 524288;             // total ~247 MB

  u16*   Xb   = (u16*)(ws + oXb);
  u16*   XbT  = (u16*)(ws + oXT);
  u16*   P    = (u16*)(ws + oP);
  float* Qall = (float*)(ws + oQall);
  u16*   Qp   = (u16*)(ws + oQp);
  float* qbw  = (float*)(ws + oQb);
  float* sums = (float*)(ws + oSums);
  float* nrm  = (float*)(ws + oNrm);
  float* Hws  = (float*)(ws + oH);
  float* ppw  = (float*)(ws + oPP);
  float* cntw = (float*)(ws + oCNT);

  kz_zero<<<(2 * BB * M_PAD + 255) / 256, 256, 0, stream>>>(sums, 2 * BB * M_PAD);
  k0_q<<<M_PAD, 256, 0, stream>>>(cat, typ, var, spc, Wcat, bcat, Wtype, btype,
                                  Wvar, bvar, Wsp, bsp, Qall);
  k1_qp<<<M_PAD, 256, 0, stream>>>(Qall, Wk, bk, Qp, qbw);
  k2_cast<<<dim3(64, 4, 32), 256, 0, stream>>>(X, Xb, XbT);
  k4_pool<<<dim3(16, 32), 256, 0, stream>>>(positions, mask, ppw, cntw);
  for (int chunk = 0; chunk < 2; ++chunk) {
    const int b0 = chunk * CHUNK_B;
    p1_scores<<<dim3(32, 6, CHUNK_B), 256, 0, stream>>>(Xb, Qp, qbw, mask, P, sums, b0);
    p2_h<<<dim3(2, 11, CHUNK_B), 256, 0, stream>>>(P, XbT, sums, Hws, nrm, b0);
  }
  k5_final<<<32, 256, 0, stream>>>(Hws, nrm, ppw, cntw, log_tau, Wg1, bg1, Wg2, bg2,
                                   Wo, bo, lng, lnb, lvlw, (float*)d_out);
}

// Round 3
// 750.053 us; speedup vs baseline: 1.7586x; 1.1334x over previous
//
#include <hip/hip_runtime.h>

typedef unsigned short u16;
typedef short v8s __attribute__((ext_vector_type(8)));
typedef float v4f __attribute__((ext_vector_type(4)));

union U16x8 { uint4 u4; v8s s8; u16 us[8]; };

__device__ __forceinline__ u16 f2bf(float x) {
  unsigned int u = __float_as_uint(x);
  u += 0x7fffu + ((u >> 16) & 1u);
  return (u16)(u >> 16);
}

#define GLOBAL_AS __attribute__((address_space(1)))
#define LDS_AS __attribute__((address_space(3)))
__device__ __forceinline__ void async16(const void* g, void* l) {
  __builtin_amdgcn_global_load_lds((const GLOBAL_AS unsigned int*)g,
                                   (LDS_AS unsigned int*)l, 16, 0, 0);
}

// ---------------- constants ----------------
#define BB 32
#define NN 4096
#define DD 256
#define M_TOT 672
#define M_PAD 704

// ---------------- KZ: zero sums+nrm+zacc ----------------
__global__ void kz_zero(float* __restrict__ p, int n) {
  int i = blockIdx.x * 256 + threadIdx.x;
  if (i < n) p[i] = 0.f;
}

// ---------------- K0: Q_all[m] = codes @ Wq^T + bq ----------------
__global__ void k0_q(const float* __restrict__ cat, const float* __restrict__ typ,
                     const float* __restrict__ var, const float* __restrict__ spc,
                     const float* __restrict__ Wcat, const float* __restrict__ bcat,
                     const float* __restrict__ Wtype, const float* __restrict__ btype,
                     const float* __restrict__ Wvar, const float* __restrict__ bvar,
                     const float* __restrict__ Wsp, const float* __restrict__ bsp,
                     float* __restrict__ Qall) {
  __shared__ float cl[DD];
  const int m = blockIdx.x, tid = threadIdx.x;
  const float* codes = nullptr; const float* W = nullptr; const float* bia = nullptr; int r = 0;
  if (m < 16)       { codes = cat; r = m;       W = Wcat;  bia = bcat; }
  else if (m < 144) { codes = typ; r = m - 16;  W = Wtype; bia = btype; }
  else if (m < 656) { codes = var; r = m - 144; W = Wvar;  bia = bvar; }
  else if (m < 672) { codes = spc; r = m - 656; W = Wsp;   bia = bsp; }
  cl[tid] = (m < M_TOT) ? codes[r * DD + tid] : 0.f;
  __syncthreads();
  if (m < M_TOT) {
    float acc = bia[tid];
    const float4* w4 = (const float4*)(W + (size_t)tid * DD);
    const float4* c4 = (const float4*)cl;
    #pragma unroll 8
    for (int k = 0; k < 64; ++k) {
      float4 a = c4[k], b = w4[k];
      acc += a.x * b.x + a.y * b.y + a.z * b.z + a.w * b.w;
    }
    Qall[m * DD + tid] = acc;
  } else {
    Qall[m * DD + tid] = 0.f;
  }
}

// ---------------- K1: Qp = Qall @ Wk (bf16), qbw = Qall . bk ----------------
__global__ void k1_qp(const float* __restrict__ Qall, const float* __restrict__ Wk,
                      const float* __restrict__ bk, u16* __restrict__ Qp,
                      float* __restrict__ qbw) {
  __shared__ float ql[DD];
  __shared__ float red[4];
  const int m = blockIdx.x, tid = threadIdx.x;
  ql[tid] = Qall[m * DD + tid];
  __syncthreads();
  float acc = 0.f;
  for (int j = 0; j < DD; ++j) acc += ql[j] * Wk[(size_t)j * DD + tid];
  Qp[m * DD + tid] = f2bf(acc);
  float p = ql[tid] * bk[tid];
  #pragma unroll
  for (int off = 32; off > 0; off >>= 1) p += __shfl_down(p, off, 64);
  if ((tid & 63) == 0) red[tid >> 6] = p;
  __syncthreads();
  if (tid == 0) qbw[m] = red[0] + red[1] + red[2] + red[3];
}

// ---------------- K2: X fp32 -> bf16 in two layouts ----------------
__global__ void k2_cast(const float* __restrict__ X, u16* __restrict__ Xb,
                        u16* __restrict__ XbT) {
  __shared__ u16 tl[64][72];
  const int n0 = blockIdx.x * 64, d0 = blockIdx.y * 64, b = blockIdx.z;
  const int tid = threadIdx.x;
  const int nl = tid >> 4, d4 = tid & 15;
  #pragma unroll
  for (int rr = 0; rr < 4; ++rr) {
    const int n = n0 + nl + rr * 16;
    float4 v = *(const float4*)(X + ((size_t)b * NN + n) * DD + d0 + d4 * 4);
    ushort4 h;
    h.x = f2bf(v.x); h.y = f2bf(v.y); h.z = f2bf(v.z); h.w = f2bf(v.w);
    *(ushort4*)(Xb + ((size_t)b * NN + n) * DD + d0 + d4 * 4) = h;
    *(ushort4*)(&tl[nl + rr * 16][d4 * 4]) = h;
  }
  __syncthreads();
  const int dl = tid >> 4, n4 = tid & 15;
  #pragma unroll
  for (int rr = 0; rr < 4; ++rr) {
    const int d = dl + rr * 16;
    ushort4 h;
    h.x = tl[n4 * 4 + 0][d]; h.y = tl[n4 * 4 + 1][d];
    h.z = tl[n4 * 4 + 2][d]; h.w = tl[n4 * 4 + 3][d];
    *(ushort4*)(XbT + ((size_t)b * DD + d0 + d) * NN + n0 + n4 * 4) = h;
  }
}

// ---------------- P1: P = exp(clip(Qp.Xb^T/16 + qb)), rowsums ----------------
__global__ __launch_bounds__(256, 2) void p1_scores(
    const u16* __restrict__ Xb, const u16* __restrict__ Qp,
    const float* __restrict__ qbw, const unsigned char* __restrict__ mask,
    u16* __restrict__ P, float* __restrict__ sums, int b0) {
  __shared__ u16 sA[128 * 64];  // 16 KB
  __shared__ u16 sB[128 * 64];  // 16 KB
  const int tid = threadIdx.x;
  const int lane = tid & 63, w = tid >> 6;
  const int q = lane >> 4, c16 = lane & 15;
  const int n0 = blockIdx.x * 128, m0 = blockIdx.y * 128;
  const int b = b0 + blockIdx.z;
  const int wm = (w >> 1) * 64, wn = (w & 1) * 64;

  float qv[4][4];
  unsigned char mk[4];
  #pragma unroll
  for (int mi = 0; mi < 4; ++mi)
    #pragma unroll
    for (int r = 0; r < 4; ++r) {
      int row = m0 + wm + mi * 16 + q * 4 + r;
      qv[mi][r] = qbw[row < M_PAD ? row : M_PAD - 1];
    }
  #pragma unroll
  for (int ni = 0; ni < 4; ++ni)
    mk[ni] = mask[(size_t)b * NN + n0 + wn + ni * 16 + c16];

  v4f acc[4][4];
  #pragma unroll
  for (int mi = 0; mi < 4; ++mi)
    #pragma unroll
    for (int ni = 0; ni < 4; ++ni) acc[mi][ni] = (v4f){0.f, 0.f, 0.f, 0.f};

  const u16* Xbase = Xb + (size_t)b * NN * DD;
  for (int ks = 0; ks < 4; ++ks) {
    __syncthreads();
    #pragma unroll
    for (int i = 0; i < 4; ++i) {
      const int c = i * 256 + tid;
      const int row = c >> 3, kc = (c & 7) * 8;
      int gm = m0 + row; gm = gm < M_PAD ? gm : M_PAD - 1;
      async16(Qp + (size_t)gm * DD + ks * 64 + kc, sA + c * 8);
      async16(Xbase + (size_t)(n0 + row) * DD + ks * 64 + kc, sB + c * 8);
    }
    __syncthreads();
    #pragma unroll
    for (int kk = 0; kk < 2; ++kk) {
      v8s af[4], bf[4];
      #pragma unroll
      for (int mi = 0; mi < 4; ++mi) {
        U16x8 u; u.u4 = *(const uint4*)(sA + (wm + mi * 16 + c16) * 64 + kk * 32 + q * 8);
        af[mi] = u.s8;
      }
      #pragma unroll
      for (int ni = 0; ni < 4; ++ni) {
        U16x8 u; u.u4 = *(const uint4*)(sB + (wn + ni * 16 + c16) * 64 + kk * 32 + q * 8);
        bf[ni] = u.s8;
      }
      #pragma unroll
      for (int mi = 0; mi < 4; ++mi)
        #pragma unroll
        for (int ni = 0; ni < 4; ++ni)
          acc[mi][ni] = __builtin_amdgcn_mfma_f32_16x16x32_bf16(af[mi], bf[ni], acc[mi][ni], 0, 0, 0);
    }
  }

  float rs[4][4];
  #pragma unroll
  for (int mi = 0; mi < 4; ++mi)
    #pragma unroll
    for (int r = 0; r < 4; ++r) rs[mi][r] = 0.f;

  #pragma unroll
  for (int mi = 0; mi < 4; ++mi) {
    #pragma unroll
    for (int ni = 0; ni < 4; ++ni) {
      #pragma unroll
      for (int r = 0; r < 4; ++r) {
        float s = (acc[mi][ni][r] + qv[mi][r]) * 0.0625f;
        s = fminf(fmaxf(s, -50.f), 50.f);
        s = mk[ni] ? s : -50.f;
        float p = __expf(s);
        rs[mi][r] += p;
        const int row = m0 + wm + mi * 16 + q * 4 + r;
        if (row < M_TOT)
          P[((size_t)(b - b0) * M_TOT + row) * NN + n0 + wn + ni * 16 + c16] = f2bf(p);
      }
    }
  }
  #pragma unroll
  for (int mi = 0; mi < 4; ++mi) {
    #pragma unroll
    for (int r = 0; r < 4; ++r) {
      float v = rs[mi][r];
      v += __shfl_xor(v, 1, 64);
      v += __shfl_xor(v, 2, 64);
      v += __shfl_xor(v, 4, 64);
      v += __shfl_xor(v, 8, 64);
      const int row = m0 + wm + mi * 16 + q * 4 + r;
      if (c16 == 0 && row < M_TOT)
        atomicAdd(&sums[(size_t)b * M_PAD + row], v);
    }
  }
}

// ---------------- P2: H = (P . XbT^T)/sums, norm partials ----------------
__global__ __launch_bounds__(256, 4) void p2_h(
    const u16* __restrict__ P, const u16* __restrict__ XbT,
    const float* __restrict__ sums, float* __restrict__ Hws,
    float* __restrict__ nrm, int b0) {
  __shared__ u16 sA[64 * 64];   // 8 KB
  __shared__ u16 sB[128 * 64];  // 16 KB
  const int tid = threadIdx.x;
  const int lane = tid & 63, w = tid >> 6;
  const int q = lane >> 4, c16 = lane & 15;
  const int d0 = blockIdx.x * 128, m0 = blockIdx.y * 64;
  const int b = b0 + blockIdx.z;
  const int wm = (w >> 1) * 32, wd = (w & 1) * 64;

  v4f acc[2][4];
  #pragma unroll
  for (int mi = 0; mi < 2; ++mi)
    #pragma unroll
    for (int ni = 0; ni < 4; ++ni) acc[mi][ni] = (v4f){0.f, 0.f, 0.f, 0.f};

  const u16* Pb = P + (size_t)(b - b0) * M_TOT * NN;
  const u16* Tb = XbT + ((size_t)b * DD + d0) * NN;

  for (int ks = 0; ks < NN / 64; ++ks) {
    __syncthreads();
    #pragma unroll
    for (int i = 0; i < 2; ++i) {
      const int c = i * 256 + tid;
      const int row = c >> 3, kc = (c & 7) * 8;
      int gm = m0 + row; gm = gm < M_TOT ? gm : M_TOT - 1;
      async16(Pb + (size_t)gm * NN + ks * 64 + kc, sA + c * 8);
    }
    #pragma unroll
    for (int i = 0; i < 4; ++i) {
      const int c = i * 256 + tid;
      const int row = c >> 3, kc = (c & 7) * 8;
      async16(Tb + (size_t)row * NN + ks * 64 + kc, sB + c * 8);
    }
    __syncthreads();
    #pragma unroll
    for (int kk = 0; kk < 2; ++kk) {
      v8s af[2], bf[4];
      #pragma unroll
      for (int mi = 0; mi < 2; ++mi) {
        U16x8 u; u.u4 = *(const uint4*)(sA + (wm + mi * 16 + c16) * 64 + kk * 32 + q * 8);
        af[mi] = u.s8;
      }
      #pragma unroll
      for (int ni = 0; ni < 4; ++ni) {
        U16x8 u; u.u4 = *(const uint4*)(sB + (wd + ni * 16 + c16) * 64 + kk * 32 + q * 8);
        bf[ni] = u.s8;
      }
      #pragma unroll
      for (int mi = 0; mi < 2; ++mi)
        #pragma unroll
        for (int ni = 0; ni < 4; ++ni)
          acc[mi][ni] = __builtin_amdgcn_mfma_f32_16x16x32_bf16(af[mi], bf[ni], acc[mi][ni], 0, 0, 0);
    }
  }

  float sv[2][4], ns[2][4];
  #pragma unroll
  for (int mi = 0; mi < 2; ++mi)
    #pragma unroll
    for (int r = 0; r < 4; ++r) {
      const int row = m0 + wm + mi * 16 + q * 4 + r;
      sv[mi][r] = sums[(size_t)b * M_PAD + row];
      ns[mi][r] = 0.f;
    }
  #pragma unroll
  for (int mi = 0; mi < 2; ++mi) {
    #pragma unroll
    for (int ni = 0; ni < 4; ++ni) {
      #pragma unroll
      for (int r = 0; r < 4; ++r) {
        const int row = m0 + wm + mi * 16 + q * 4 + r;
        float h = acc[mi][ni][r] / sv[mi][r];
        ns[mi][r] += h * h;
        Hws[((size_t)b * M_PAD + row) * DD + d0 + wd + ni * 16 + c16] = h;
      }
    }
  }
  #pragma unroll
  for (int mi = 0; mi < 2; ++mi) {
    #pragma unroll
    for (int r = 0; r < 4; ++r) {
      float v = ns[mi][r];
      v += __shfl_xor(v, 1, 64);
      v += __shfl_xor(v, 2, 64);
      v += __shfl_xor(v, 4, 64);
      v += __shfl_xor(v, 8, 64);
      const int row = m0 + wm + mi * 16 + q * 4 + r;
      if (c16 == 0 && row < M_TOT)
        atomicAdd(&nrm[(size_t)b * M_PAD + row], v);
    }
  }
}

// ---------------- K4: masked position pooling partials ----------------
__global__ void k4_pool(const float* __restrict__ pos, const unsigned char* __restrict__ mask,
                        float* __restrict__ pp, float* __restrict__ cnt) {
  __shared__ float sp[4][256];
  __shared__ float sc[4];
  const int cx = blockIdx.x, b = blockIdx.y, tid = threadIdx.x;
  const int nl = tid >> 6, d4 = tid & 63;
  const int n0 = cx * 256;
  float4 acc = {0.f, 0.f, 0.f, 0.f};
  float c = 0.f;
  for (int i = 0; i < 64; ++i) {
    const int n = n0 + i * 4 + nl;
    const float m = mask[(size_t)b * NN + n] ? 1.f : 0.f;
    c += m;
    float4 v = *(const float4*)(pos + ((size_t)b * NN + n) * DD + d4 * 4);
    acc.x += m * v.x; acc.y += m * v.y; acc.z += m * v.z; acc.w += m * v.w;
  }
  *(float4*)(&sp[nl][d4 * 4]) = acc;
  if (d4 == 0) sc[nl] = c;
  __syncthreads();
  pp[((size_t)b * 16 + cx) * DD + tid] = sp[0][tid] + sp[1][tid] + sp[2][tid] + sp[3][tid];
  if (tid == 0) cnt[b * 16 + cx] = sc[0] + sc[1] + sc[2] + sc[3];
}

// ---------------- K5a: gating weights per batch ----------------
__device__ void softmax_sparsify(const float* in, int nn, float* outp, float thr) {
  float mx = -3.4e38f;
  for (int i = 0; i < nn; ++i) mx = fmaxf(mx, in[i]);
  float s = 0.f;
  for (int i = 0; i < nn; ++i) { float e = __expf(in[i] - mx); outp[i] = e; s += e; }
  float s2 = 0.f;
  for (int i = 0; i < nn; ++i) {
    float v = outp[i] / s;
    v = (v > thr) ? v : 0.f;
    outp[i] = v; s2 += v;
  }
  const float inv = 1.f / (s2 + 1e-8f);
  for (int i = 0; i < nn; ++i) outp[i] *= inv;
}

__global__ void k5a_weights(const float* __restrict__ nrm, const float* __restrict__ log_tau,
                            const float* __restrict__ lvlw, float* __restrict__ wbufG) {
  __shared__ float wr[M_TOT];
  __shared__ float wcat[16], wtyp[128], wvar[512], wsp[16], lw[4];
  __shared__ float tmp[128];
  const int b = blockIdx.x, tid = threadIdx.x;
  const float tau = fminf(fmaxf(__expf(log_tau[0]) + 0.1f, 0.1f), 2.0f);
  for (int m = tid; m < M_TOT; m += 256)
    wr[m] = sqrtf(nrm[(size_t)b * M_PAD + m]) / tau;
  __syncthreads();
  if (tid == 0) {
    softmax_sparsify(wr, 16, wcat, 0.1f);
    for (int i = 0; i < 128; ++i) tmp[i] = wr[16 + i] * wcat[i >> 3];
    softmax_sparsify(tmp, 128, wtyp, 0.05f);
    for (int i = 0; i < 512; ++i) wvar[i] = wr[144 + i] * wtyp[i >> 2];
    softmax_sparsify(wvar, 512, wvar, 0.025f);
    softmax_sparsify(wr + 656, 16, wsp, 0.1f);
    float mx = fmaxf(fmaxf(lvlw[0], lvlw[1]), fmaxf(lvlw[2], lvlw[3]));
    float s = 0.f;
    for (int i = 0; i < 4; ++i) { lw[i] = __expf(lvlw[i] - mx); s += lw[i]; }
    for (int i = 0; i < 4; ++i) lw[i] /= s;
  }
  __syncthreads();
  for (int m = tid; m < M_TOT; m += 256) {
    float v;
    if (m < 16)       v = lw[0] * wcat[m];
    else if (m < 144) v = lw[1] * wtyp[m - 16];
    else if (m < 656) v = lw[2] * wvar[m - 144];
    else              v = lw[3] * wsp[m - 656];
    wbufG[(size_t)b * M_PAD + m] = v;
  }
}

// ---------------- K5b: z partials (parallel over m-chunks) ----------------
__global__ void k5b_z(const float* __restrict__ Hws, const float* __restrict__ wbufG,
                      float* __restrict__ zacc) {
  const int mc = blockIdx.x, b = blockIdx.y, tid = threadIdx.x;
  const float* Hb = Hws + (size_t)b * M_PAD * DD;
  const float* wb = wbufG + (size_t)b * M_PAD;
  float acc = 0.f;
  #pragma unroll 4
  for (int i = 0; i < 84; ++i) {
    const int m = mc * 84 + i;
    acc += wb[m] * Hb[(size_t)m * DD + tid];
  }
  atomicAdd(&zacc[(size_t)b * DD + tid], acc);
}

// ---------------- K5c: gate MLP + out proj + LayerNorm ----------------
__global__ void k5c_mlp(const float* __restrict__ zacc, const float* __restrict__ pp,
                        const float* __restrict__ cnt,
                        const float* __restrict__ Wg1, const float* __restrict__ bg1,
                        const float* __restrict__ Wg2, const float* __restrict__ bg2,
                        const float* __restrict__ Wo, const float* __restrict__ bo,
                        const float* __restrict__ lng, const float* __restrict__ lnb,
                        float* __restrict__ out) {
  __shared__ float zb[DD], pb[DD], hb[DD], zg[DD];
  __shared__ float red[8];
  const int b = blockIdx.x, tid = threadIdx.x;
  const int lane = tid & 63, w = tid >> 6;

  float p = 0.f, c = 0.f;
  for (int ch = 0; ch < 16; ++ch) {
    p += pp[((size_t)b * 16 + ch) * DD + tid];
    c += cnt[b * 16 + ch];
  }
  zb[tid] = zacc[(size_t)b * DD + tid];
  pb[tid] = p / (c + 1e-8f);
  __syncthreads();

  float h = bg1[tid];
  {
    const float4* w4 = (const float4*)(Wg1 + (size_t)tid * 512);
    const float4* z4 = (const float4*)zb;
    const float4* p4 = (const float4*)pb;
    for (int k = 0; k < 64; ++k) {
      float4 a = z4[k], bb = w4[k];
      h += a.x * bb.x + a.y * bb.y + a.z * bb.z + a.w * bb.w;
    }
    for (int k = 0; k < 64; ++k) {
      float4 a = p4[k], bb = w4[64 + k];
      h += a.x * bb.x + a.y * bb.y + a.z * bb.z + a.w * bb.w;
    }
  }
  h = 0.5f * h * (1.f + erff(h * 0.70710678118654752f));
  hb[tid] = h;
  __syncthreads();

  float g = bg2[tid];
  {
    const float4* w4 = (const float4*)(Wg2 + (size_t)tid * DD);
    const float4* h4 = (const float4*)hb;
    for (int k = 0; k < 64; ++k) {
      float4 a = h4[k], bb = w4[k];
      g += a.x * bb.x + a.y * bb.y + a.z * bb.z + a.w * bb.w;
    }
  }
  g = 1.f / (1.f + __expf(-g));
  zg[tid] = zb[tid] * g;
  __syncthreads();

  float y = bo[tid];
  {
    const float4* w4 = (const float4*)(Wo + (size_t)tid * DD);
    const float4* z4 = (const float4*)zg;
    for (int k = 0; k < 64; ++k) {
      float4 a = z4[k], bb = w4[k];
      y += a.x * bb.x + a.y * bb.y + a.z * bb.z + a.w * bb.w;
    }
  }

  float s = y;
  #pragma unroll
  for (int off = 32; off > 0; off >>= 1) s += __shfl_xor(s, off, 64);
  if (lane == 0) red[w] = s;
  __syncthreads();
  const float mu = (red[0] + red[1] + red[2] + red[3]) * (1.f / 256.f);
  float dv = (y - mu) * (y - mu);
  #pragma unroll
  for (int off = 32; off > 0; off >>= 1) dv += __shfl_xor(dv, off, 64);
  if (lane == 0) red[4 + w] = dv;
  __syncthreads();
  const float var = (red[4] + red[5] + red[6] + red[7]) * (1.f / 256.f);
  out[(size_t)b * DD + tid] = (y - mu) / sqrtf(var + 1e-5f) * lng[tid] + lnb[tid];
}

// ---------------- launch ----------------
extern "C" void kernel_launch(void* const* d_in, const int* in_sizes, int n_in,
                              void* d_out, int out_size, void* d_ws, size_t ws_size,
                              hipStream_t stream) {
  const float* X          = (const float*)d_in[0];
  const float* positions  = (const float*)d_in[1];
  const unsigned char* mask = (const unsigned char*)d_in[2];
  const float* cat  = (const float*)d_in[3];
  const float* typ  = (const float*)d_in[4];
  const float* var  = (const float*)d_in[5];
  const float* spc  = (const float*)d_in[6];
  const float* log_tau = (const float*)d_in[7];
  const float* Wk   = (const float*)d_in[8];   const float* bk    = (const float*)d_in[9];
  const float* Wcat = (const float*)d_in[10];  const float* bcat  = (const float*)d_in[11];
  const float* Wtype= (const float*)d_in[12];  const float* btype = (const float*)d_in[13];
  const float* Wvar = (const float*)d_in[14];  const float* bvar  = (const float*)d_in[15];
  const float* Wsp  = (const float*)d_in[16];  const float* bsp   = (const float*)d_in[17];
  const float* Wg1  = (const float*)d_in[18];  const float* bg1   = (const float*)d_in[19];
  const float* Wg2  = (const float*)d_in[20];  const float* bg2   = (const float*)d_in[21];
  const float* Wo   = (const float*)d_in[22];  const float* bo    = (const float*)d_in[23];
  const float* lng  = (const float*)d_in[24];  const float* lnb   = (const float*)d_in[25];
  const float* lvlw = (const float*)d_in[26];

  char* ws = (char*)d_ws;
  size_t off = 0;
  auto alloc = [&](size_t bytes) { size_t o = off; off = (off + bytes + 255) & ~255ULL; return o; };
  const size_t oXb   = alloc((size_t)BB * NN * DD * 2);   // 64 MiB
  const size_t oXT   = alloc((size_t)BB * DD * NN * 2);   // 64 MiB
  const size_t oQall = alloc((size_t)M_PAD * DD * 4);
  const size_t oQp   = alloc((size_t)M_PAD * DD * 2);
  const size_t oQb   = alloc((size_t)M_PAD * 4);
  const size_t oSums = alloc((size_t)BB * M_PAD * 4);
  const size_t oNrm  = alloc((size_t)BB * M_PAD * 4);
  const size_t oZac  = alloc((size_t)BB * DD * 4);
  const size_t oWbf  = alloc((size_t)BB * M_PAD * 4);
  const size_t oH    = alloc((size_t)BB * M_PAD * DD * 4);  // 22 MiB
  const size_t oPP   = alloc((size_t)BB * 16 * DD * 4);
  const size_t oCNT  = alloc((size_t)BB * 16 * 4);
  const size_t oP    = alloc(0);  // P goes last, variable size

  const size_t pFull = (size_t)BB * M_TOT * NN * 2;        // 176 MiB
  const int chunks  = (ws_size >= oP + pFull) ? 1 : 2;
  const int chunkB  = BB / chunks;

  u16*   Xb   = (u16*)(ws + oXb);
  u16*   XbT  = (u16*)(ws + oXT);
  float* Qall = (float*)(ws + oQall);
  u16*   Qp   = (u16*)(ws + oQp);
  float* qbw  = (float*)(ws + oQb);
  float* sums = (float*)(ws + oSums);
  float* nrm  = (float*)(ws + oNrm);
  float* zacc = (float*)(ws + oZac);
  float* wbfG = (float*)(ws + oWbf);
  float* Hws  = (float*)(ws + oH);
  float* ppw  = (float*)(ws + oPP);
  float* cntw = (float*)(ws + oCNT);
  u16*   P    = (u16*)(ws + oP);

  // zero sums + nrm + zacc (contiguous region)
  const int nzero = 2 * BB * M_PAD + BB * DD;
  kz_zero<<<(nzero + 255) / 256, 256, 0, stream>>>(sums, nzero);
  k0_q<<<M_PAD, 256, 0, stream>>>(cat, typ, var, spc, Wcat, bcat, Wtype, btype,
                                  Wvar, bvar, Wsp, bsp, Qall);
  k1_qp<<<M_PAD, 256, 0, stream>>>(Qall, Wk, bk, Qp, qbw);
  k2_cast<<<dim3(64, 4, 32), 256, 0, stream>>>(X, Xb, XbT);
  k4_pool<<<dim3(16, 32), 256, 0, stream>>>(positions, mask, ppw, cntw);
  for (int chunk = 0; chunk < chunks; ++chunk) {
    const int b0 = chunk * chunkB;
    p1_scores<<<dim3(32, 6, chunkB), 256, 0, stream>>>(Xb, Qp, qbw, mask, P, sums, b0);
    p2_h<<<dim3(2, 11, chunkB), 256, 0, stream>>>(P, XbT, sums, Hws, nrm, b0);
  }
  k5a_weights<<<32, 256, 0, stream>>>(nrm, log_tau, lvlw, wbfG);
  k5b_z<<<dim3(8, 32), 256, 0, stream>>>(Hws, wbfG, zacc);
  k5c_mlp<<<32, 256, 0, stream>>>(zacc, ppw, cntw, Wg1, bg1, Wg2, bg2, Wo, bo,
                                  lng, lnb, (float*)d_out);
}